// Round 1
// baseline (20957.590 us; speedup 1.0000x reference)
//
#include <hip/hip_runtime.h>
#include <hip/hip_bf16.h>
#include <cstdint>
#include <cstddef>

// LSTM encoder: B=64, T=512, D=256, UNITS=1024, gates G=4096 (i|f|g|o).
// z_t = x_t @ W + h_{t-1} @ U + b  -> gates -> c,h.  Fused K = 1024(U) + 256(W) = 1280.
// Persistent kernel: 256 WGs, WG owns 4 units (16 gate cols). Grid barrier per step.

#define NWG    256
#define KSTEPS 40          // 1280 / 32
#define SEQ_N  33554432    // 64*512*1024

typedef __attribute__((ext_vector_type(8))) short short8;
typedef __attribute__((ext_vector_type(4))) float floatx4;

static __device__ __forceinline__ short f2bf(float f) {
  __hip_bfloat16 h = __float2bfloat16(f);
  return *reinterpret_cast<short*>(&h);
}
static __device__ __forceinline__ float sigm(float x) { return 1.f / (1.f + __expf(-x)); }
static __device__ __forceinline__ float tanh_fast(float x) {
  float xc = fminf(fmaxf(x, -15.f), 15.f);
  float e  = __expf(2.f * xc);
  return (e - 1.f) / (e + 1.f);
}

// ---- prep: pack [U;W] into per-WG MFMA B-fragment order, bf16 ----
// Consumption: lane L of a wave reads upack[((wg*40+kk)*64 + L)*8 + j]
//   == Bsrc[k = kk*32 + (L>>4)*8 + j][gatecol = (n>>2)*1024 + wg*4 + (n&3)], n=L&15
__global__ void pack_weights(const float* __restrict__ W, const float* __restrict__ U,
                             short* __restrict__ upack) {
  int idx  = blockIdx.x * 256 + threadIdx.x;   // 0 .. 256*40*64-1 exact
  int lane = idx & 63;
  int kk   = (idx >> 6) % KSTEPS;
  int wg   = idx / (KSTEPS * 64);
  int quad = lane >> 4, n = lane & 15;
  int col  = (n >> 2) * 1024 + wg * 4 + (n & 3);
  int k0   = kk * 32 + quad * 8;
  short8 v;
#pragma unroll
  for (int j = 0; j < 8; ++j) {
    int k = k0 + j;
    float f = (k < 1024) ? U[(size_t)k * 4096 + col] : W[(size_t)(k - 1024) * 4096 + col];
    v[j] = f2bf(f);
  }
  *reinterpret_cast<short8*>(upack + (size_t)idx * 8) = v;
}

__global__ void convert_x(const float* __restrict__ x, short* __restrict__ xbf) {
  int idx = blockIdx.x * 256 + threadIdx.x;    // 8 elems each, 64*512*256/8 exact
  const float* xp = x + (size_t)idx * 8;
  short8 v;
#pragma unroll
  for (int j = 0; j < 8; ++j) v[j] = f2bf(xp[j]);
  *reinterpret_cast<short8*>(xbf + (size_t)idx * 8) = v;
}

// ---- persistent stepper ----
__global__ __launch_bounds__(256, 1) void lstm_persist(
    const short* __restrict__ xbf,    // [64][512][256] bf16
    const short* __restrict__ upack,  // packed B frags
    const float* __restrict__ bias,   // [4096] f32
    short* __restrict__ hbuf,         // [2][64][1024] bf16 (zeroed)
    int*   __restrict__ bar,          // [512] ints (zeroed)
    float* __restrict__ out)          // seq | h_last | c_last
{
  __shared__ float zlds[64 * 17];
  const int wg   = blockIdx.x;
  const int tid  = threadIdx.x;
  const int wave = tid >> 6;
  const int lane = tid & 63;
  const int quad = lane >> 4;
  const int l15  = lane & 15;
  const int arow = wave * 16 + l15;          // A-operand batch row (m = lane&15)
  // elementwise mapping: thread -> (batch eb, unit-in-wg ej)
  const int eb   = tid >> 2;
  const int ej   = tid & 3;
  const int unit = wg * 4 + ej;
  const float bi = bias[unit];
  const float bf = bias[1024 + unit];
  const float bg = bias[2048 + unit];
  const float bo = bias[3072 + unit];
  float creg = 0.f;

  const short* bbase = upack + (size_t)wg * KSTEPS * 64 * 8 + (size_t)lane * 8;
  const short* xrow  = xbf + (size_t)arow * 512 * 256 + quad * 8;

  for (int t = 0; t < 512; ++t) {
    const short* hsrc = hbuf + ((t & 1) << 16);
    short*       hdst = hbuf + (((t + 1) & 1) << 16);

    floatx4 acc0 = {0.f, 0.f, 0.f, 0.f};
    floatx4 acc1 = {0.f, 0.f, 0.f, 0.f};
    {
      const short* ap = hsrc + arow * 1024 + quad * 8;
      const short* bp = bbase;
#pragma unroll 4
      for (int kk = 0; kk < 16; ++kk) {      // h@U part: K 0..1023
        short8 a0 = *reinterpret_cast<const short8*>(ap);
        short8 b0 = *reinterpret_cast<const short8*>(bp);
        short8 a1 = *reinterpret_cast<const short8*>(ap + 32);
        short8 b1 = *reinterpret_cast<const short8*>(bp + 512);
        ap += 64; bp += 1024;
        acc0 = __builtin_amdgcn_mfma_f32_16x16x32_bf16(a0, b0, acc0, 0, 0, 0);
        acc1 = __builtin_amdgcn_mfma_f32_16x16x32_bf16(a1, b1, acc1, 0, 0, 0);
      }
      const short* xp = xrow + t * 256;
#pragma unroll
      for (int kk = 0; kk < 4; ++kk) {       // x@W part: K 1024..1279
        short8 a0 = *reinterpret_cast<const short8*>(xp);
        short8 b0 = *reinterpret_cast<const short8*>(bp);
        short8 a1 = *reinterpret_cast<const short8*>(xp + 32);
        short8 b1 = *reinterpret_cast<const short8*>(bp + 512);
        xp += 64; bp += 1024;
        acc0 = __builtin_amdgcn_mfma_f32_16x16x32_bf16(a0, b0, acc0, 0, 0, 0);
        acc1 = __builtin_amdgcn_mfma_f32_16x16x32_bf16(a1, b1, acc1, 0, 0, 0);
      }
    }
    acc0 = acc0 + acc1;

    // C layout: col = lane&15, row = quad*4 + r  -> zlds[batchrow][gatecol]
#pragma unroll
    for (int r = 0; r < 4; ++r)
      zlds[(wave * 16 + quad * 4 + r) * 17 + l15] = acc0[r];
    __syncthreads();

    float zi = zlds[eb * 17 + 0  + ej] + bi;
    float zf = zlds[eb * 17 + 4  + ej] + bf;
    float zg = zlds[eb * 17 + 8  + ej] + bg;
    float zo = zlds[eb * 17 + 12 + ej] + bo;
    float ig = sigm(zi), fg = sigm(zf), gg = tanh_fast(zg), og = sigm(zo);
    float cn = fg * creg + ig * gg;
    creg = cn;
    float hn = og * tanh_fast(cn);

    hdst[eb * 1024 + unit] = f2bf(hn);
    out[((size_t)eb * 512 + t) * 1024 + unit] = hn;
    if (t == 511) {
      out[(size_t)SEQ_N + eb * 1024 + unit] = hn;                 // h_last
      out[(size_t)SEQ_N + 65536 + eb * 1024 + unit] = cn;         // c_last
    }

    if (t < 511) {
      __threadfence();               // make h stores device-visible
      __syncthreads();
      if (tid == 0) {
        __hip_atomic_fetch_add(&bar[t], 1, __ATOMIC_RELEASE, __HIP_MEMORY_SCOPE_AGENT);
        while (__hip_atomic_load(&bar[t], __ATOMIC_ACQUIRE, __HIP_MEMORY_SCOPE_AGENT) < NWG) {
          __builtin_amdgcn_s_sleep(1);
        }
      }
      __syncthreads();
    }
  }
}

extern "C" void kernel_launch(void* const* d_in, const int* in_sizes, int n_in,
                              void* d_out, int out_size, void* d_ws, size_t ws_size,
                              hipStream_t stream) {
  const float* x    = (const float*)d_in[0];
  const float* W    = (const float*)d_in[1];
  const float* U    = (const float*)d_in[2];
  const float* bias = (const float*)d_in[3];
  float* out = (float*)d_out;
  char* ws = (char*)d_ws;

  short* upack = (short*)ws;                      // 10,485,760 B
  short* xbf   = (short*)(ws + 10485760);         // 16,777,216 B
  short* hbuf  = (short*)(ws + 27262976);         //    262,144 B (2 buffers)
  int*   bar   = (int*)  (ws + 27525120);         //      2,048 B
  (void)in_sizes; (void)n_in; (void)out_size; (void)ws_size;

  hipMemsetAsync(hbuf, 0, 262144 + 2048, stream);           // h0 = 0, barrier counters = 0
  pack_weights<<<2560, 256, 0, stream>>>(W, U, upack);
  convert_x<<<4096, 256, 0, stream>>>(x, xbf);
  lstm_persist<<<NWG, 256, 0, stream>>>(xbf, upack, bias, hbuf, bar, out);
}